// Round 3
// baseline (665.483 us; speedup 1.0000x reference)
//
#include <hip/hip_runtime.h>
#include <math.h>

#define Bn   8
#define Cn   256
#define HWn  4096
#define FB   (Cn * HWn)      // 1048576 elems per batch-field
#define NTOT (Bn * FB)       // 8388608 elems per field
#define TEND 1.0
#define EPSK 1e-12f
#define NT   32              // apply N-tile (positions)
#define RS   40              // Ph/Pl row stride (shorts) — 80B, 16B-aligned
#define TS   36              // tred row stride (floats)
#define WTS  36              // wt row stride (floats), 144B 16B-aligned

typedef float f32x4 __attribute__((ext_vector_type(4)));
typedef short bf16x8 __attribute__((ext_vector_type(8)));

__device__ inline float b2f(unsigned int u) {
    return __uint_as_float(u << 16);
}
__device__ inline unsigned short f2b(float f) {  // RNE
    unsigned u = __float_as_uint(f);
    unsigned r = u + 0x7FFFu + ((u >> 16) & 1u);
    return (unsigned short)(r >> 16);
}

// acc layout (floats, 8 batches each):
//   D[k][j] at acc[(k*8+j)*8 + b];  Nsq[j] at acc[512 + j*8 + b];  coords at acc+576

__global__ void init_kernel(float* __restrict__ p) {
    for (int i = threadIdx.x; i < 1024; i += 256) p[i] = 0.0f;
}

// ---- split W into bf16 hi/lo in MFMA-A staged layout ----
// layout: Whs[((kc*16+mt)*64+lane)*8+j] = bf16 of W[mt*16+(lane&15)][kc*32+(lane>>4)*8+j]
__global__ void wsplit_kernel(const float* __restrict__ W,
                              unsigned short* __restrict__ Whs,
                              unsigned short* __restrict__ Wls) {
    int kc = blockIdx.x, mt = blockIdx.y, l = threadIdx.x;
    int m = mt * 16 + (l & 15);
    int k0 = kc * 32 + (l >> 4) * 8;
#pragma unroll
    for (int j = 0; j < 8; ++j) {
        float wv = W[m * 256 + k0 + j];
        unsigned short h = f2b(wv);
        unsigned short lo = f2b(wv - b2f(h));
        int idx = ((kc * 16 + mt) * 64 + l) * 8 + j;
        Whs[idx] = h; Wls[idx] = lo;
    }
}

// ================= fused Krylov step K (K = 0..7) =================
// NT=32 tile, 1024 blocks (4/CU) for BW-latency hiding; dbuf Ph/Pl (1 barrier/kc).
// phase 1 : x = U_K = w - sum_{j<K} cj_j * basis_j  -> Q_{K-1} bf16, Nsq[K], t
// phase 2 : w' = W @ (s0 .* (x - t))  via split-bf16 MFMA   (Z eliminated)
// epilogue: LDS transpose -> coalesced w' write + coalesced dots D[K][j]
template <int K>
__global__ __launch_bounds__(256, 4) void step_kernel(
        const float* __restrict__ v, const float* __restrict__ s0,
        const unsigned short* __restrict__ Whs, const unsigned short* __restrict__ Wls,
        unsigned short* __restrict__ Qb, float* __restrict__ acc,
        float* __restrict__ w) {
    // union: phase1/2 use Ph/Pl (x2 dbuf) + tred; epilogue reuses region as wt
    __shared__ __align__(16) char smem_u[36864];
    short* Ph0  = (short*)smem_u;                 // 2560 B
    short* Ph1  = (short*)(smem_u + 2560);
    short* Pl0  = (short*)(smem_u + 5120);
    short* Pl1  = (short*)(smem_u + 7680);
    float* tred = (float*)(smem_u + 10240);       // 4608 B
    float* wt   = (float*)smem_u;                 // 256*WTS*4 = 36864 B (epilogue)
    __shared__ float ts[NT];
    __shared__ float nred[4];
    __shared__ float dred[4][8];
    const int tid = threadIdx.x;
    const int b = blockIdx.y;
    const int sbase = blockIdx.x * NT;
    const size_t boff = (size_t)b * FB;
    const int lane = tid & 63, wvi = tid >> 6;
    const int mbase = wvi * 64;
    const int cg = tid >> 3;         // 0..31 channel sub-group
    const int pos = (tid & 7) * 4;   // 0..28

    // ---- CGS coefficients from previous step's dots ----
    float cj[K > 0 ? K : 1];
    if (K > 0) {
        float mm[K > 0 ? K : 1];
        mm[0] = sqrtf(acc[512 + b]);
#pragma unroll
        for (int j = 1; j < K; ++j) mm[j] = sqrtf(acc[512 + j * 8 + b]) + EPSK * mm[j - 1];
#pragma unroll
        for (int j = 0; j < K; ++j)
            cj[j] = acc[((K - 1) * 8 + j) * 8 + b] / (mm[j] * mm[j]);
    }
    unsigned short* QK = Qb + (size_t)(K > 0 ? K - 1 : 0) * NTOT;

    // ---- phase 1 ----
    float tp[4] = {0.f, 0.f, 0.f, 0.f};
    float np = 0.f;
#pragma unroll
    for (int cc = 0; cc < 8; ++cc) {
        int c = cc * 32 + cg;
        size_t off = boff + (size_t)c * HWn + sbase + pos;
        float4 sv = *(const float4*)(s0 + off);
        float se[4] = {sv.x, sv.y, sv.z, sv.w};
        if (K == 0) {
            float4 xv = *(const float4*)(v + off);
            float xe[4] = {xv.x, xv.y, xv.z, xv.w};
#pragma unroll
            for (int i = 0; i < 4; ++i) {
                np = fmaf(xe[i], xe[i], np);
                tp[i] = fmaf(xe[i], se[i], tp[i]);
            }
        } else {
            float4 wv4 = *(const float4*)(w + off);
            float4 vv4 = *(const float4*)(v + off);
            float xe[4];
            xe[0] = fmaf(-cj[0], vv4.x, wv4.x);
            xe[1] = fmaf(-cj[0], vv4.y, wv4.y);
            xe[2] = fmaf(-cj[0], vv4.z, wv4.z);
            xe[3] = fmaf(-cj[0], vv4.w, wv4.w);
#pragma unroll
            for (int j = 1; j < K; ++j) {
                ushort4 u = *(const ushort4*)(Qb + (size_t)(j - 1) * NTOT + off);
                xe[0] = fmaf(-cj[j], b2f(u.x), xe[0]);
                xe[1] = fmaf(-cj[j], b2f(u.y), xe[1]);
                xe[2] = fmaf(-cj[j], b2f(u.z), xe[2]);
                xe[3] = fmaf(-cj[j], b2f(u.w), xe[3]);
            }
            unsigned int h0 = f2b(xe[0]), h1 = f2b(xe[1]);
            unsigned int h2 = f2b(xe[2]), h3 = f2b(xe[3]);
            ushort4 o;
            o.x = (unsigned short)h0; o.y = (unsigned short)h1;
            o.z = (unsigned short)h2; o.w = (unsigned short)h3;
            *(ushort4*)(QK + off) = o;
            float xr[4] = {b2f(h0), b2f(h1), b2f(h2), b2f(h3)};
#pragma unroll
            for (int i = 0; i < 4; ++i) {
                np = fmaf(xr[i], xr[i], np);
                tp[i] = fmaf(xr[i], se[i], tp[i]);
            }
        }
    }
    for (int off2 = 32; off2 > 0; off2 >>= 1) np += __shfl_down(np, off2);
    if (lane == 0) nred[wvi] = np;
    *(float4*)(tred + cg * TS + pos) = *(float4*)tp;
    __syncthreads();
    if (tid < NT) {
        float s = 0.f;
#pragma unroll
        for (int g = 0; g < 32; ++g) s += tred[g * TS + tid];
        ts[tid] = s;
    }
    if (tid == 0)
        atomicAdd(&acc[512 + K * 8 + b], nred[0] + nred[1] + nred[2] + nred[3]);
    __syncthreads();

    // ---- phase 2: MFMA over 8 k-chunks, double-buffered staging ----
    f32x4 ac[4][2];
#pragma unroll
    for (int i = 0; i < 4; ++i)
#pragma unroll
        for (int j = 0; j < 2; ++j) ac[i][j] = (f32x4){0.f, 0.f, 0.f, 0.f};

    auto stage = [&](int kc, int bb) {
        int c = kc * 32 + cg;
        size_t off = boff + (size_t)c * HWn + sbase + pos;
        float4 sv = *(const float4*)(s0 + off);
        float se[4] = {sv.x, sv.y, sv.z, sv.w};
        float xr[4];
        if (K == 0) {
            float4 xv = *(const float4*)(v + off);
            xr[0] = xv.x; xr[1] = xv.y; xr[2] = xv.z; xr[3] = xv.w;
        } else {
            ushort4 u = *(const ushort4*)(QK + off);   // just written, cache-hot
            xr[0] = b2f(u.x); xr[1] = b2f(u.y); xr[2] = b2f(u.z); xr[3] = b2f(u.w);
        }
        short* ph = bb ? Ph1 : Ph0;
        short* pl = bb ? Pl1 : Pl0;
#pragma unroll
        for (int i = 0; i < 4; ++i) {
            float p = se[i] * (xr[i] - ts[pos + i]);
            unsigned short h = f2b(p);
            unsigned short l = f2b(p - b2f(h));
            ph[(pos + i) * RS + cg] = (short)h;
            pl[(pos + i) * RS + cg] = (short)l;
        }
    };
    stage(0, 0);
    for (int kc = 0; kc < 8; ++kc) {
        __syncthreads();               // buf[kc&1] staged; buf[(kc+1)&1] reads done
        if (kc < 7) stage(kc + 1, (kc + 1) & 1);
        const short* ph = (kc & 1) ? Ph1 : Ph0;
        const short* pl = (kc & 1) ? Pl1 : Pl0;
        bf16x8 ah[4], al[4], bh[2], bl[2];
#pragma unroll
        for (int rt = 0; rt < 4; ++rt) {
            int mt = (mbase >> 4) + rt;
            ah[rt] = *(const bf16x8*)(Whs + (size_t)kc * 8192 + (mt * 64 + lane) * 8);
            al[rt] = *(const bf16x8*)(Wls + (size_t)kc * 8192 + (mt * 64 + lane) * 8);
        }
#pragma unroll
        for (int ct = 0; ct < 2; ++ct) {
            int n = ct * 16 + (lane & 15);
            int k8 = (lane >> 4) * 8;
            bh[ct] = *(const bf16x8*)(ph + n * RS + k8);
            bl[ct] = *(const bf16x8*)(pl + n * RS + k8);
        }
#pragma unroll
        for (int rt = 0; rt < 4; ++rt)
#pragma unroll
            for (int ct = 0; ct < 2; ++ct) {
                ac[rt][ct] = __builtin_amdgcn_mfma_f32_16x16x32_bf16(ah[rt], bh[ct], ac[rt][ct], 0, 0, 0);
                ac[rt][ct] = __builtin_amdgcn_mfma_f32_16x16x32_bf16(ah[rt], bl[ct], ac[rt][ct], 0, 0, 0);
                ac[rt][ct] = __builtin_amdgcn_mfma_f32_16x16x32_bf16(al[rt], bh[ct], ac[rt][ct], 0, 0, 0);
            }
    }

    // ---- epilogue: LDS transpose -> coalesced w' write + coalesced dots ----
    __syncthreads();   // MFMA ds_reads done; wt aliases Ph/Pl
#pragma unroll
    for (int rt = 0; rt < 4; ++rt)
#pragma unroll
        for (int ct = 0; ct < 2; ++ct) {
            int r0 = mbase + rt * 16 + (lane >> 4) * 4;
            int col = ct * 16 + (lane & 15);
#pragma unroll
            for (int reg = 0; reg < 4; ++reg)
                wt[(r0 + reg) * WTS + col] = ac[rt][ct][reg];
        }
    __syncthreads();
    float dp[K + 1];
#pragma unroll
    for (int j = 0; j <= K; ++j) dp[j] = 0.f;
#pragma unroll
    for (int rr = 0; rr < 8; ++rr) {
        int rabs = rr * 32 + (tid >> 3);
        int col = (tid & 7) * 4;
        const float* src = wt + rabs * WTS + col;
        float4 wv4 = {src[0], src[1], src[2], src[3]};
        size_t idx = boff + (size_t)rabs * HWn + sbase + col;
        *(float4*)(w + idx) = wv4;
        float4 vv4 = *(const float4*)(v + idx);
        dp[0] = fmaf(wv4.x, vv4.x, dp[0]);
        dp[0] = fmaf(wv4.y, vv4.y, dp[0]);
        dp[0] = fmaf(wv4.z, vv4.z, dp[0]);
        dp[0] = fmaf(wv4.w, vv4.w, dp[0]);
#pragma unroll
        for (int j = 1; j <= K; ++j) {
            ushort4 u = *(const ushort4*)(Qb + (size_t)(j - 1) * NTOT + idx);
            dp[j] = fmaf(wv4.x, b2f(u.x), dp[j]);
            dp[j] = fmaf(wv4.y, b2f(u.y), dp[j]);
            dp[j] = fmaf(wv4.z, b2f(u.z), dp[j]);
            dp[j] = fmaf(wv4.w, b2f(u.w), dp[j]);
        }
    }
#pragma unroll
    for (int j = 0; j <= K; ++j) {
        float q = dp[j];
        for (int off2 = 32; off2 > 0; off2 >>= 1) q += __shfl_down(q, off2);
        if (lane == 0) dred[wvi][j] = q;
    }
    __syncthreads();
    if (tid <= K)
        atomicAdd(&acc[(K * 8 + tid) * 8 + b],
                  dred[0][tid] + dred[1][tid] + dred[2][tid] + dred[3][tid]);
}

// ---------------- expm of 9x9 per batch (fp64); emits combine coeffs ----------
__global__ __launch_bounds__(128) void expm_kernel(const float* __restrict__ acc,
                                                   float* __restrict__ coordsOut) {
    __shared__ double Am[81], Pm[81], Tm[81];
    __shared__ double ssc;
    __shared__ int sn;
    const int b = blockIdx.x;
    const int t = threadIdx.x;
    const int r = t / 9, c = t % 9;
    double m[8];
    m[0] = sqrt((double)acc[512 + b]);
    for (int j = 1; j < 8; ++j) m[j] = sqrt((double)acc[512 + j * 8 + b]) + 1e-12 * m[j - 1];
    if (t < 81) {
        double val = 0.0;
        if (r < 8 && c < 8) {
            if (r <= c) val = TEND * (double)acc[(c * 8 + r) * 8 + b] / (m[r] * m[c]);
            else if (r == c + 1) val = TEND * sqrt((double)acc[512 + r * 8 + b]) / m[c];
        }
        if (r == 0 && c == 8) val = TEND;
        Am[t] = val;
    }
    __syncthreads();
    if (t == 0) {
        double mx = 0.0;
        for (int rr = 0; rr < 9; ++rr) {
            double s = 0.0;
            for (int cc = 0; cc < 9; ++cc) s += fabs(Am[rr * 9 + cc]);
            if (s > mx) mx = s;
        }
        int n = 0;
        while (mx > 0.25 && n < 48) { mx *= 0.5; ++n; }
        double sc = 1.0;
        for (int ii = 0; ii < n; ++ii) sc *= 0.5;
        sn = n; ssc = sc;
    }
    __syncthreads();
    if (t < 81) Am[t] *= ssc;
    __syncthreads();
    if (t < 81) Pm[t] = (r == c) ? 1.0 : 0.0;
    __syncthreads();
    for (int i = 20; i >= 1; --i) {
        if (t < 81) {
            double s = 0.0;
            for (int k = 0; k < 9; ++k) s += Am[r * 9 + k] * Pm[k * 9 + c];
            Tm[t] = ((r == c) ? 1.0 : 0.0) + s / (double)i;
        }
        __syncthreads();
        if (t < 81) Pm[t] = Tm[t];
        __syncthreads();
    }
    int n = sn;
    for (int q = 0; q < n; ++q) {
        if (t < 81) {
            double s = 0.0;
            for (int k = 0; k < 9; ++k) s += Pm[r * 9 + k] * Pm[k * 9 + c];
            Tm[t] = s;
        }
        __syncthreads();
        if (t < 81) Pm[t] = Tm[t];
        __syncthreads();
    }
    if (t < 8) coordsOut[b * 8 + t] = (float)(Pm[t * 9 + 8] * m[0] / m[t]);
}

__device__ inline void unp8(uint4 u, float* f) {
    f[0] = b2f(u.x & 0xFFFFu); f[1] = b2f(u.x >> 16);
    f[2] = b2f(u.y & 0xFFFFu); f[3] = b2f(u.y >> 16);
    f[4] = b2f(u.z & 0xFFFFu); f[5] = b2f(u.z >> 16);
    f[6] = b2f(u.w & 0xFFFFu); f[7] = b2f(u.w >> 16);
}

// ------ out = coeff_0*v + sum_{j=1..7} coeff_j * U_j (bf16) ------
__global__ __launch_bounds__(256) void combine_kernel(const unsigned short* __restrict__ Qb,
                                                      const float* __restrict__ v,
                                                      const float* __restrict__ coords,
                                                      float* __restrict__ out) {
    int b = blockIdx.y;
    const size_t boff = (size_t)b * FB;
    float cf[8];
#pragma unroll
    for (int j = 0; j < 8; ++j) cf[j] = coords[b * 8 + j];
    const float4* vv = (const float4*)(v + boff);
    const uint4* uv[8];
#pragma unroll
    for (int j = 1; j < 8; ++j)
        uv[j] = (const uint4*)(Qb + (size_t)(j - 1) * NTOT + boff);
    int i = blockIdx.x * 256 + threadIdx.x;
    float4* ov = (float4*)(out + boff);
#pragma unroll
    for (int r = 0; r < 2; ++r) {
        int idx = i + r * 65536;
        float4 v0 = vv[2 * idx], v1 = vv[2 * idx + 1];
        float a[8] = {cf[0] * v0.x, cf[0] * v0.y, cf[0] * v0.z, cf[0] * v0.w,
                      cf[0] * v1.x, cf[0] * v1.y, cf[0] * v1.z, cf[0] * v1.w};
#pragma unroll
        for (int j = 1; j < 8; ++j) {
            uint4 u = uv[j][idx];
            float ue[8]; unp8(u, ue);
#pragma unroll
            for (int e = 0; e < 8; ++e) a[e] = fmaf(cf[j], ue[e], a[e]);
        }
        float4 o0 = {a[0], a[1], a[2], a[3]};
        float4 o1 = {a[4], a[5], a[6], a[7]};
        ov[2 * idx] = o0; ov[2 * idx + 1] = o1;
    }
}

extern "C" void kernel_launch(void* const* d_in, const int* in_sizes, int n_in,
                              void* d_out, int out_size, void* d_ws, size_t ws_size,
                              hipStream_t stream) {
    const float* s0 = (const float*)d_in[0];
    const float* v  = (const float*)d_in[1];
    const float* W  = (const float*)d_in[2];
    float* out = (float*)d_out;

    // ws (floats): [acc 576 | coords 64 | pad->1024 | Whs 32768 | Wls 32768 | Qb bf16 7*NTOT/2]
    float* ws     = (float*)d_ws;
    float* acc    = ws;
    float* coords = ws + 576;
    unsigned short* Whs = (unsigned short*)(ws + 1024);
    unsigned short* Wls = (unsigned short*)(ws + 1024 + 32768);
    unsigned short* Qb  = (unsigned short*)(ws + 1024 + 65536);  // 7 bf16 fields
    float* w      = out;   // working A-output (fp32), updated in place per step

    init_kernel<<<dim3(1), dim3(256), 0, stream>>>(ws);
    wsplit_kernel<<<dim3(8, 16), dim3(64), 0, stream>>>(W, Whs, Wls);

    dim3 ga(128, 8), blk(256);
#define STEPK(K) step_kernel<K><<<ga, blk, 0, stream>>>(v, s0, Whs, Wls, Qb, acc, w);
    STEPK(0) STEPK(1) STEPK(2) STEPK(3) STEPK(4) STEPK(5) STEPK(6) STEPK(7)
#undef STEPK

    expm_kernel<<<dim3(8), dim3(128), 0, stream>>>(acc, coords);
    combine_kernel<<<dim3(256, 8), blk, 0, stream>>>(Qb, v, coords, out);
}

// Round 4
// 579.079 us; speedup vs baseline: 1.1492x; 1.1492x over previous
//
#include <hip/hip_runtime.h>
#include <math.h>

#define Bn   8
#define Cn   256
#define HWn  4096
#define FB   (Cn * HWn)      // 1048576 elems per batch-field
#define NTOT (Bn * FB)       // 8388608 elems per field
#define TEND 1.0
#define EPSK 1e-12f
#define NT   64              // apply N-tile (positions) — full 256B lines
#define RS   40              // Ph/Pl row stride (shorts) — 80B: b128 r/w conflict-free
#define WTS  68              // wt row stride (floats)

typedef float f32x4 __attribute__((ext_vector_type(4)));
typedef short bf16x8 __attribute__((ext_vector_type(8)));

__device__ inline float b2f(unsigned int u) {
    return __uint_as_float(u << 16);
}
__device__ inline unsigned short f2b(float f) {  // RNE
    unsigned u = __float_as_uint(f);
    unsigned r = u + 0x7FFFu + ((u >> 16) & 1u);
    return (unsigned short)(r >> 16);
}

// acc layout (floats, 8 batches each):
//   D[k][j] at acc[(k*8+j)*8 + b];  Nsq[j] at acc[512 + j*8 + b];  coords at acc+576

__global__ void init_kernel(float* __restrict__ p) {
    for (int i = threadIdx.x; i < 1024; i += 256) p[i] = 0.0f;
}

// ---- split W into bf16 hi/lo in MFMA-A staged layout ----
// layout: Whs[((kc*16+mt)*64+lane)*8+j] = bf16 of W[mt*16+(lane&15)][kc*32+(lane>>4)*8+j]
__global__ void wsplit_kernel(const float* __restrict__ W,
                              unsigned short* __restrict__ Whs,
                              unsigned short* __restrict__ Wls) {
    int kc = blockIdx.x, mt = blockIdx.y, l = threadIdx.x;
    int m = mt * 16 + (l & 15);
    int k0 = kc * 32 + (l >> 4) * 8;
#pragma unroll
    for (int j = 0; j < 8; ++j) {
        float wv = W[m * 256 + k0 + j];
        unsigned short h = f2b(wv);
        unsigned short lo = f2b(wv - b2f(h));
        int idx = ((kc * 16 + mt) * 64 + l) * 8 + j;
        Whs[idx] = h; Wls[idx] = lo;
    }
}

// ================= fused Krylov step (K = -1: Z-build; K = 0..7: step) ===========
// K>=0 : single pass per k-chunk: x = w - sum cj*basis (CGS), write Q_{K-1} bf16,
//        P = s0*xr hi/lo -> LDS -> MFMA  (t accumulated on the side, no t-barrier)
//        epilogue: w' = acc - Z*t (Z=W@s0 bf16 hi/lo), coalesced write + dots D[K][j]
// K=-1 : P = s0 hi/lo, epilogue writes Z as bf16 hi/lo pair.
// Numerics == baseline: w' = W@(s0.*xr) - Z.*t, t = colsum(s0.*xr)
template <int K>
__global__ __launch_bounds__(256, 2) void step_kernel(
        const float* __restrict__ v, const float* __restrict__ s0,
        const unsigned short* __restrict__ Whs, const unsigned short* __restrict__ Wls,
        unsigned short* __restrict__ Qb, float* __restrict__ acc,
        float* __restrict__ w,
        unsigned short* __restrict__ Zh, unsigned short* __restrict__ Zl) {
    // union: main loop uses Ph/Pl dbuf (20 KB); epilogue reuses region as wt (34 KB)
    __shared__ __align__(16) char smem_u[34816];
    short* Ph0 = (short*)smem_u;                  // 64*RS*2 = 5120 B each
    short* Ph1 = (short*)(smem_u + 5120);
    short* Pl0 = (short*)(smem_u + 10240);
    short* Pl1 = (short*)(smem_u + 15360);
    float* wt  = (float*)smem_u;                  // 128*WTS*4 = 34816 B (epilogue)
    __shared__ float tred[4][64];
    __shared__ float ts[NT];
    __shared__ float nred[4];
    __shared__ float dred[4][8];

    const int tid = threadIdx.x;
    const int b = blockIdx.y;
    const int sbase = blockIdx.x * NT;
    const size_t boff = (size_t)b * FB;
    const int lane = tid & 63, wvi = tid >> 6;
    const int mbase = wvi * 64;
    const int ch8 = wvi * 8;          // channel octet within 32-chunk
    const int p   = lane;             // local position 0..63

    // ---- CGS coefficients from previous step's dots ----
    float cj[K > 0 ? K : 1];
    if (K > 0) {
        float mm[K > 0 ? K : 1];
        mm[0] = sqrtf(acc[512 + b]);
#pragma unroll
        for (int j = 1; j < K; ++j) mm[j] = sqrtf(acc[512 + j * 8 + b]) + EPSK * mm[j - 1];
#pragma unroll
        for (int j = 0; j < K; ++j)
            cj[j] = acc[((K - 1) * 8 + j) * 8 + b] / (mm[j] * mm[j]);
    }
    unsigned short* QK = Qb + (size_t)(K > 0 ? K - 1 : 0) * NTOT;

    float tp = 0.f, np = 0.f;

    auto stage = [&](int kc, int bb) {
        const int c0 = kc * 32 + ch8;
        const size_t off = boff + (size_t)c0 * HWn + sbase + p;
        short* ph = bb ? Ph1 : Ph0;
        short* pl = bb ? Pl1 : Pl0;
        bf16x8 hv, lv;
#pragma unroll
        for (int e = 0; e < 8; ++e) {
            const size_t oe = off + (size_t)e * HWn;
            float s = s0[oe];
            float pe;
            if (K < 0) {
                pe = s;
            } else if (K == 0) {
                float xv = v[oe];
                np = fmaf(xv, xv, np);
                tp = fmaf(xv, s, tp);
                pe = s * xv;
            } else {
                float xe = w[oe];
                xe = fmaf(-cj[0], v[oe], xe);
#pragma unroll
                for (int j = 1; j < K; ++j)
                    xe = fmaf(-cj[j], b2f(Qb[(size_t)(j - 1) * NTOT + oe]), xe);
                unsigned short hx = f2b(xe);
                QK[oe] = hx;
                float xr = b2f(hx);
                np = fmaf(xr, xr, np);
                tp = fmaf(xr, s, tp);
                pe = s * xr;
            }
            unsigned short h = f2b(pe);
            hv[e] = (short)h;
            lv[e] = (short)f2b(pe - b2f(h));
        }
        *(bf16x8*)(ph + p * RS + ch8) = hv;   // single b128, conflict-free
        *(bf16x8*)(pl + p * RS + ch8) = lv;
    };

    f32x4 ac[4][4];
#pragma unroll
    for (int i = 0; i < 4; ++i)
#pragma unroll
        for (int j = 0; j < 4; ++j) ac[i][j] = (f32x4){0.f, 0.f, 0.f, 0.f};

    stage(0, 0);
    for (int kc = 0; kc < 8; ++kc) {
        __syncthreads();               // buf[kc&1] staged; buf[kc^1] reads done
        if (kc < 7) stage(kc + 1, (kc + 1) & 1);
        const short* ph = (kc & 1) ? Ph1 : Ph0;
        const short* pl = (kc & 1) ? Pl1 : Pl0;
        bf16x8 ah[4], al[4], bh[4], bl[4];
#pragma unroll
        for (int rt = 0; rt < 4; ++rt) {
            int mt = (mbase >> 4) + rt;
            ah[rt] = *(const bf16x8*)(Whs + (size_t)kc * 8192 + (mt * 64 + lane) * 8);
            al[rt] = *(const bf16x8*)(Wls + (size_t)kc * 8192 + (mt * 64 + lane) * 8);
        }
#pragma unroll
        for (int ct = 0; ct < 4; ++ct) {
            int n = ct * 16 + (lane & 15);
            int k8 = (lane >> 4) * 8;
            bh[ct] = *(const bf16x8*)(ph + n * RS + k8);
            bl[ct] = *(const bf16x8*)(pl + n * RS + k8);
        }
#pragma unroll
        for (int rt = 0; rt < 4; ++rt)
#pragma unroll
            for (int ct = 0; ct < 4; ++ct) {
                ac[rt][ct] = __builtin_amdgcn_mfma_f32_16x16x32_bf16(ah[rt], bh[ct], ac[rt][ct], 0, 0, 0);
                ac[rt][ct] = __builtin_amdgcn_mfma_f32_16x16x32_bf16(ah[rt], bl[ct], ac[rt][ct], 0, 0, 0);
                ac[rt][ct] = __builtin_amdgcn_mfma_f32_16x16x32_bf16(al[rt], bh[ct], ac[rt][ct], 0, 0, 0);
            }
    }

    __syncthreads();   // all MFMA LDS reads done
    if (K >= 0) {
        tred[wvi][p] = tp;
        float q = np;
        for (int off2 = 32; off2 > 0; off2 >>= 1) q += __shfl_down(q, off2);
        if (lane == 0) nred[wvi] = q;
    }
    __syncthreads();
    if (K >= 0) {
        if (tid < NT)
            ts[tid] = tred[0][tid] + tred[1][tid] + tred[2][tid] + tred[3][tid];
        if (tid == 0)
            atomicAdd(&acc[512 + K * 8 + b], nred[0] + nred[1] + nred[2] + nred[3]);
    }

    // ---- epilogue: LDS transpose (2 groups of 128 rows) -> coalesced out ----
    float dp[K >= 0 ? K + 1 : 1];
#pragma unroll
    for (int j = 0; j < (K >= 0 ? K + 1 : 1); ++j) dp[j] = 0.f;
#pragma unroll
    for (int g = 0; g < 2; ++g) {
        __syncthreads();   // wt (aliases Ph/Pl) safe / prev group done
        if ((wvi >> 1) == g) {
            int rl = (wvi & 1) * 64;
#pragma unroll
            for (int rt = 0; rt < 4; ++rt)
#pragma unroll
                for (int ct = 0; ct < 4; ++ct) {
                    int r0 = rl + rt * 16 + (lane >> 4) * 4;
                    int ccol = ct * 16 + (lane & 15);
#pragma unroll
                    for (int reg = 0; reg < 4; ++reg)
                        wt[(r0 + reg) * WTS + ccol] = ac[rt][ct][reg];
                }
        }
        __syncthreads();
#pragma unroll
        for (int rr = 0; rr < 8; ++rr) {
            int rlocal = rr * 16 + (tid >> 4);
            int rabs = g * 128 + rlocal;
            int col = (tid & 15) * 4;
            const float* src = wt + rlocal * WTS + col;
            float4 wv4 = {src[0], src[1], src[2], src[3]};
            size_t idx = boff + (size_t)rabs * HWn + sbase + col;
            if (K < 0) {
                ushort4 zh4, zl4;
                unsigned short h0 = f2b(wv4.x), h1 = f2b(wv4.y);
                unsigned short h2 = f2b(wv4.z), h3 = f2b(wv4.w);
                zh4.x = h0; zh4.y = h1; zh4.z = h2; zh4.w = h3;
                zl4.x = f2b(wv4.x - b2f(h0)); zl4.y = f2b(wv4.y - b2f(h1));
                zl4.z = f2b(wv4.z - b2f(h2)); zl4.w = f2b(wv4.w - b2f(h3));
                *(ushort4*)(Zh + idx) = zh4;
                *(ushort4*)(Zl + idx) = zl4;
            } else {
                ushort4 zh4 = *(const ushort4*)(Zh + idx);
                ushort4 zl4 = *(const ushort4*)(Zl + idx);
                float z0 = b2f(zh4.x) + b2f(zl4.x), z1 = b2f(zh4.y) + b2f(zl4.y);
                float z2 = b2f(zh4.z) + b2f(zl4.z), z3 = b2f(zh4.w) + b2f(zl4.w);
                float4 wf;
                wf.x = wv4.x - z0 * ts[col + 0];
                wf.y = wv4.y - z1 * ts[col + 1];
                wf.z = wv4.z - z2 * ts[col + 2];
                wf.w = wv4.w - z3 * ts[col + 3];
                *(float4*)(w + idx) = wf;
                float4 vv4 = *(const float4*)(v + idx);
                dp[0] = fmaf(wf.x, vv4.x, dp[0]);
                dp[0] = fmaf(wf.y, vv4.y, dp[0]);
                dp[0] = fmaf(wf.z, vv4.z, dp[0]);
                dp[0] = fmaf(wf.w, vv4.w, dp[0]);
#pragma unroll
                for (int j = 1; j <= (K >= 0 ? K : 0); ++j) {
                    ushort4 u = *(const ushort4*)(Qb + (size_t)(j - 1) * NTOT + idx);
                    dp[j] = fmaf(wf.x, b2f(u.x), dp[j]);
                    dp[j] = fmaf(wf.y, b2f(u.y), dp[j]);
                    dp[j] = fmaf(wf.z, b2f(u.z), dp[j]);
                    dp[j] = fmaf(wf.w, b2f(u.w), dp[j]);
                }
            }
        }
    }
    if (K >= 0) {
#pragma unroll
        for (int j = 0; j <= K; ++j) {
            float q = dp[j];
            for (int off2 = 32; off2 > 0; off2 >>= 1) q += __shfl_down(q, off2);
            if (lane == 0) dred[wvi][j] = q;
        }
        __syncthreads();
        if (tid <= K)
            atomicAdd(&acc[(K * 8 + tid) * 8 + b],
                      dred[0][tid] + dred[1][tid] + dred[2][tid] + dred[3][tid]);
    }
}

// ---------------- expm of 9x9 per batch (fp64); emits combine coeffs ----------
__global__ __launch_bounds__(128) void expm_kernel(const float* __restrict__ acc,
                                                   float* __restrict__ coordsOut) {
    __shared__ double Am[81], Pm[81], Tm[81];
    __shared__ double ssc;
    __shared__ int sn;
    const int b = blockIdx.x;
    const int t = threadIdx.x;
    const int r = t / 9, c = t % 9;
    double m[8];
    m[0] = sqrt((double)acc[512 + b]);
    for (int j = 1; j < 8; ++j) m[j] = sqrt((double)acc[512 + j * 8 + b]) + 1e-12 * m[j - 1];
    if (t < 81) {
        double val = 0.0;
        if (r < 8 && c < 8) {
            if (r <= c) val = TEND * (double)acc[(c * 8 + r) * 8 + b] / (m[r] * m[c]);
            else if (r == c + 1) val = TEND * sqrt((double)acc[512 + r * 8 + b]) / m[c];
        }
        if (r == 0 && c == 8) val = TEND;
        Am[t] = val;
    }
    __syncthreads();
    if (t == 0) {
        double mx = 0.0;
        for (int rr = 0; rr < 9; ++rr) {
            double s = 0.0;
            for (int cc = 0; cc < 9; ++cc) s += fabs(Am[rr * 9 + cc]);
            if (s > mx) mx = s;
        }
        int n = 0;
        while (mx > 0.25 && n < 48) { mx *= 0.5; ++n; }
        double sc = 1.0;
        for (int ii = 0; ii < n; ++ii) sc *= 0.5;
        sn = n; ssc = sc;
    }
    __syncthreads();
    if (t < 81) Am[t] *= ssc;
    __syncthreads();
    if (t < 81) Pm[t] = (r == c) ? 1.0 : 0.0;
    __syncthreads();
    for (int i = 20; i >= 1; --i) {
        if (t < 81) {
            double s = 0.0;
            for (int k = 0; k < 9; ++k) s += Am[r * 9 + k] * Pm[k * 9 + c];
            Tm[t] = ((r == c) ? 1.0 : 0.0) + s / (double)i;
        }
        __syncthreads();
        if (t < 81) Pm[t] = Tm[t];
        __syncthreads();
    }
    int n = sn;
    for (int q = 0; q < n; ++q) {
        if (t < 81) {
            double s = 0.0;
            for (int k = 0; k < 9; ++k) s += Pm[r * 9 + k] * Pm[k * 9 + c];
            Tm[t] = s;
        }
        __syncthreads();
        if (t < 81) Pm[t] = Tm[t];
        __syncthreads();
    }
    if (t < 8) coordsOut[b * 8 + t] = (float)(Pm[t * 9 + 8] * m[0] / m[t]);
}

__device__ inline void unp8(uint4 u, float* f) {
    f[0] = b2f(u.x & 0xFFFFu); f[1] = b2f(u.x >> 16);
    f[2] = b2f(u.y & 0xFFFFu); f[3] = b2f(u.y >> 16);
    f[4] = b2f(u.z & 0xFFFFu); f[5] = b2f(u.z >> 16);
    f[6] = b2f(u.w & 0xFFFFu); f[7] = b2f(u.w >> 16);
}

// ------ out = coeff_0*v + sum_{j=1..7} coeff_j * U_j (bf16) ------
__global__ __launch_bounds__(256) void combine_kernel(const unsigned short* __restrict__ Qb,
                                                      const float* __restrict__ v,
                                                      const float* __restrict__ coords,
                                                      float* __restrict__ out) {
    int b = blockIdx.y;
    const size_t boff = (size_t)b * FB;
    float cf[8];
#pragma unroll
    for (int j = 0; j < 8; ++j) cf[j] = coords[b * 8 + j];
    const float4* vv = (const float4*)(v + boff);
    const uint4* uv[8];
#pragma unroll
    for (int j = 1; j < 8; ++j)
        uv[j] = (const uint4*)(Qb + (size_t)(j - 1) * NTOT + boff);
    int i = blockIdx.x * 256 + threadIdx.x;
    float4* ov = (float4*)(out + boff);
#pragma unroll
    for (int r = 0; r < 2; ++r) {
        int idx = i + r * 65536;
        float4 v0 = vv[2 * idx], v1 = vv[2 * idx + 1];
        float a[8] = {cf[0] * v0.x, cf[0] * v0.y, cf[0] * v0.z, cf[0] * v0.w,
                      cf[0] * v1.x, cf[0] * v1.y, cf[0] * v1.z, cf[0] * v1.w};
#pragma unroll
        for (int j = 1; j < 8; ++j) {
            uint4 u = uv[j][idx];
            float ue[8]; unp8(u, ue);
#pragma unroll
            for (int e = 0; e < 8; ++e) a[e] = fmaf(cf[j], ue[e], a[e]);
        }
        float4 o0 = {a[0], a[1], a[2], a[3]};
        float4 o1 = {a[4], a[5], a[6], a[7]};
        ov[2 * idx] = o0; ov[2 * idx + 1] = o1;
    }
}

extern "C" void kernel_launch(void* const* d_in, const int* in_sizes, int n_in,
                              void* d_out, int out_size, void* d_ws, size_t ws_size,
                              hipStream_t stream) {
    const float* s0 = (const float*)d_in[0];
    const float* v  = (const float*)d_in[1];
    const float* W  = (const float*)d_in[2];
    float* out = (float*)d_out;

    // ws (floats): [acc 576 | coords 64 | pad->1024 | Whs 32768 | Wls 32768 |
    //               Zh bf16 NTOT | Zl bf16 NTOT | Qb bf16 7*NTOT]
    float* ws     = (float*)d_ws;
    float* acc    = ws;
    float* coords = ws + 576;
    unsigned short* Whs = (unsigned short*)(ws + 1024);
    unsigned short* Wls = Whs + 65536;
    unsigned short* Zh  = (unsigned short*)(ws + 1024 + 65536);
    unsigned short* Zl  = Zh + NTOT;
    unsigned short* Qb  = Zh + 2 * (size_t)NTOT;   // 7 bf16 fields
    float* w      = out;   // working A-output (fp32), updated in place per step

    init_kernel<<<dim3(1), dim3(256), 0, stream>>>(ws);
    wsplit_kernel<<<dim3(8, 16), dim3(64), 0, stream>>>(W, Whs, Wls);

    dim3 ga(64, 8), blk(256);
    // Z = W @ s0 (once, bf16 hi/lo)
    step_kernel<-1><<<ga, blk, 0, stream>>>(v, s0, Whs, Wls, Qb, acc, w, Zh, Zl);
#define STEPK(K) step_kernel<K><<<ga, blk, 0, stream>>>(v, s0, Whs, Wls, Qb, acc, w, Zh, Zl);
    STEPK(0) STEPK(1) STEPK(2) STEPK(3) STEPK(4) STEPK(5) STEPK(6) STEPK(7)
#undef STEPK

    expm_kernel<<<dim3(8), dim3(128), 0, stream>>>(acc, coords);
    combine_kernel<<<dim3(256, 8), blk, 0, stream>>>(Qb, v, coords, out);
}

// Round 5
// 531.487 us; speedup vs baseline: 1.2521x; 1.0895x over previous
//
#include <hip/hip_runtime.h>
#include <math.h>

#define Bn   8
#define Cn   256
#define HWn  4096
#define FB   (Cn * HWn)      // 1048576 elems per batch-field
#define NTOT (Bn * FB)       // 8388608 elems per field
#define TEND 1.0
#define EPSK 1e-12f
#define NT   64              // apply N-tile (positions) — full 256B lines
#define RS   40              // Ph/Pl row stride (shorts) — b128 reads bank-balanced
#define WTS  68              // wt row stride (floats)

typedef float f32x4 __attribute__((ext_vector_type(4)));
typedef short bf16x8 __attribute__((ext_vector_type(8)));

__device__ inline float b2f(unsigned int u) {
    return __uint_as_float(u << 16);
}
__device__ inline unsigned short f2b(float f) {  // RNE
    unsigned u = __float_as_uint(f);
    unsigned r = u + 0x7FFFu + ((u >> 16) & 1u);
    return (unsigned short)(r >> 16);
}

// acc layout (floats, 8 batches each):
//   D[k][j] at acc[(k*8+j)*8 + b];  Nsq[j] at acc[512 + j*8 + b];  coords at acc+576

__global__ void init_kernel(float* __restrict__ p) {
    for (int i = threadIdx.x; i < 1024; i += 256) p[i] = 0.0f;
}

// ---- split W into bf16 hi/lo in MFMA-A staged layout ----
// layout: Whs[((kc*16+mt)*64+lane)*8+j] = bf16 of W[mt*16+(lane&15)][kc*32+(lane>>4)*8+j]
__global__ void wsplit_kernel(const float* __restrict__ W,
                              unsigned short* __restrict__ Whs,
                              unsigned short* __restrict__ Wls) {
    int kc = blockIdx.x, mt = blockIdx.y, l = threadIdx.x;
    int m = mt * 16 + (l & 15);
    int k0 = kc * 32 + (l >> 4) * 8;
#pragma unroll
    for (int j = 0; j < 8; ++j) {
        float wv = W[m * 256 + k0 + j];
        unsigned short h = f2b(wv);
        unsigned short lo = f2b(wv - b2f(h));
        int idx = ((kc * 16 + mt) * 64 + l) * 8 + j;
        Whs[idx] = h; Wls[idx] = lo;
    }
}

// ================= fused Krylov step (K = -1: Z-build; K = 0..7: step) ===========
// Grid: (128, 8): bx = tile(0..63) + 64*mhalf. Each block computes 128 of 256
// output channels (M-split doubles grid -> 4 blocks/CU). Stage (CGS + P build)
// is duplicated across the mhalf pair (same XCD under default dispatch -> L2 hits);
// only mhalf=0 writes Q_K / Nsq. Thread = 4 pos x 2 ch -> float4/ushort4 loads.
// Numerics == baseline: w' = W@(s0.*xr) - Z.*t, t = colsum(s0.*xr), Z = W@s0.
template <int K>
__global__ __launch_bounds__(256, 4) void step_kernel(
        const float* __restrict__ v, const float* __restrict__ s0,
        const unsigned short* __restrict__ Whs, const unsigned short* __restrict__ Wls,
        unsigned short* __restrict__ Qb, float* __restrict__ acc,
        float* __restrict__ w,
        unsigned short* __restrict__ Zh, unsigned short* __restrict__ Zl) {
    // union: main loop uses Ph/Pl dbuf (20 KB); epilogue reuses region as wt (17 KB)
    __shared__ __align__(16) char smem_u[20480];
    short* Ph0 = (short*)smem_u;                  // 64*RS*2 = 5120 B each
    short* Ph1 = (short*)(smem_u + 5120);
    short* Pl0 = (short*)(smem_u + 10240);
    short* Pl1 = (short*)(smem_u + 15360);
    float* wt  = (float*)smem_u;                  // 64*WTS*4 = 17408 B (epilogue)
    __shared__ float tred[16][WTS];
    __shared__ float ts[NT];
    __shared__ float nred[4];
    __shared__ float dred[4][8];

    const int tid = threadIdx.x;
    const int b = blockIdx.y;
    const int mhalf = blockIdx.x >> 6;
    const int sbase = (blockIdx.x & 63) * NT;
    const size_t boff = (size_t)b * FB;
    const int lane = tid & 63, wvi = tid >> 6;
    const int mbase = mhalf * 128 + wvi * 32;
    const int c2 = tid >> 4;          // 0..15: channel pair {2c2, 2c2+1} in chunk
    const int pos4 = (tid & 15) * 4;  // 0..60

    // ---- CGS coefficients from previous step's dots ----
    float cj[K > 0 ? K : 1];
    if (K > 0) {
        float mm[K > 0 ? K : 1];
        mm[0] = sqrtf(acc[512 + b]);
#pragma unroll
        for (int j = 1; j < K; ++j) mm[j] = sqrtf(acc[512 + j * 8 + b]) + EPSK * mm[j - 1];
#pragma unroll
        for (int j = 0; j < K; ++j)
            cj[j] = acc[((K - 1) * 8 + j) * 8 + b] / (mm[j] * mm[j]);
    }
    unsigned short* QK = Qb + (size_t)(K > 0 ? K - 1 : 0) * NTOT;

    float tp[4] = {0.f, 0.f, 0.f, 0.f};
    float np = 0.f;

    auto stage = [&](int kc, int bb) {
        const int c0 = kc * 32 + 2 * c2;
        const size_t offA = boff + (size_t)c0 * HWn + sbase + pos4;
        short* ph = bb ? Ph1 : Ph0;
        short* pl = bb ? Pl1 : Pl0;
        float pA[4], pB[4];
#pragma unroll
        for (int h = 0; h < 2; ++h) {
            const size_t oe = offA + (size_t)h * HWn;
            float4 s4 = *(const float4*)(s0 + oe);
            float se[4] = {s4.x, s4.y, s4.z, s4.w};
            float* pr = h ? pB : pA;
            if (K < 0) {
#pragma unroll
                for (int i = 0; i < 4; ++i) pr[i] = se[i];
            } else if (K == 0) {
                float4 x4 = *(const float4*)(v + oe);
                float xe[4] = {x4.x, x4.y, x4.z, x4.w};
#pragma unroll
                for (int i = 0; i < 4; ++i) {
                    if (mhalf == 0) np = fmaf(xe[i], xe[i], np);
                    tp[i] = fmaf(xe[i], se[i], tp[i]);
                    pr[i] = se[i] * xe[i];
                }
            } else {
                float4 w4 = *(const float4*)(w + oe);
                float4 v4 = *(const float4*)(v + oe);
                float xe[4];
                xe[0] = fmaf(-cj[0], v4.x, w4.x);
                xe[1] = fmaf(-cj[0], v4.y, w4.y);
                xe[2] = fmaf(-cj[0], v4.z, w4.z);
                xe[3] = fmaf(-cj[0], v4.w, w4.w);
#pragma unroll
                for (int j = 1; j < K; ++j) {
                    ushort4 u = *(const ushort4*)(Qb + (size_t)(j - 1) * NTOT + oe);
                    xe[0] = fmaf(-cj[j], b2f(u.x), xe[0]);
                    xe[1] = fmaf(-cj[j], b2f(u.y), xe[1]);
                    xe[2] = fmaf(-cj[j], b2f(u.z), xe[2]);
                    xe[3] = fmaf(-cj[j], b2f(u.w), xe[3]);
                }
                unsigned int h0 = f2b(xe[0]), h1 = f2b(xe[1]);
                unsigned int h2 = f2b(xe[2]), h3 = f2b(xe[3]);
                if (mhalf == 0) {
                    ushort4 o;
                    o.x = (unsigned short)h0; o.y = (unsigned short)h1;
                    o.z = (unsigned short)h2; o.w = (unsigned short)h3;
                    *(ushort4*)(QK + oe) = o;
                }
                float xr[4] = {b2f(h0), b2f(h1), b2f(h2), b2f(h3)};
#pragma unroll
                for (int i = 0; i < 4; ++i) {
                    if (mhalf == 0) np = fmaf(xr[i], xr[i], np);
                    tp[i] = fmaf(xr[i], se[i], tp[i]);
                    pr[i] = se[i] * xr[i];
                }
            }
        }
        // pack both channels' bf16 hi/lo and write one b32 per buffer per position
#pragma unroll
        for (int i = 0; i < 4; ++i) {
            unsigned hA = f2b(pA[i]), hB = f2b(pB[i]);
            unsigned lA = f2b(pA[i] - b2f((unsigned short)hA));
            unsigned lB = f2b(pB[i] - b2f((unsigned short)hB));
            *(unsigned*)(ph + (pos4 + i) * RS + 2 * c2) = hA | (hB << 16);
            *(unsigned*)(pl + (pos4 + i) * RS + 2 * c2) = lA | (lB << 16);
        }
    };

    f32x4 ac[2][4];
#pragma unroll
    for (int i = 0; i < 2; ++i)
#pragma unroll
        for (int j = 0; j < 4; ++j) ac[i][j] = (f32x4){0.f, 0.f, 0.f, 0.f};

    stage(0, 0);
    for (int kc = 0; kc < 8; ++kc) {
        __syncthreads();               // buf[kc&1] staged; buf[kc^1] reads done
        if (kc < 7) stage(kc + 1, (kc + 1) & 1);
        const short* ph = (kc & 1) ? Ph1 : Ph0;
        const short* pl = (kc & 1) ? Pl1 : Pl0;
        bf16x8 ah[2], al[2], bh[4], bl[4];
#pragma unroll
        for (int rt = 0; rt < 2; ++rt) {
            int mt = (mbase >> 4) + rt;
            ah[rt] = *(const bf16x8*)(Whs + (size_t)kc * 8192 + (mt * 64 + lane) * 8);
            al[rt] = *(const bf16x8*)(Wls + (size_t)kc * 8192 + (mt * 64 + lane) * 8);
        }
#pragma unroll
        for (int ct = 0; ct < 4; ++ct) {
            int n = ct * 16 + (lane & 15);
            int k8 = (lane >> 4) * 8;
            bh[ct] = *(const bf16x8*)(ph + n * RS + k8);
            bl[ct] = *(const bf16x8*)(pl + n * RS + k8);
        }
#pragma unroll
        for (int rt = 0; rt < 2; ++rt)
#pragma unroll
            for (int ct = 0; ct < 4; ++ct) {
                ac[rt][ct] = __builtin_amdgcn_mfma_f32_16x16x32_bf16(ah[rt], bh[ct], ac[rt][ct], 0, 0, 0);
                ac[rt][ct] = __builtin_amdgcn_mfma_f32_16x16x32_bf16(ah[rt], bl[ct], ac[rt][ct], 0, 0, 0);
                ac[rt][ct] = __builtin_amdgcn_mfma_f32_16x16x32_bf16(al[rt], bh[ct], ac[rt][ct], 0, 0, 0);
            }
    }

    __syncthreads();   // all MFMA LDS reads done
    if (K >= 0) {
        *(float4*)(&tred[c2][pos4]) = *(float4*)tp;
        if (mhalf == 0) {
            float q = np;
            for (int off2 = 32; off2 > 0; off2 >>= 1) q += __shfl_down(q, off2);
            if (lane == 0) nred[wvi] = q;
        }
    }
    __syncthreads();
    if (K >= 0) {
        if (tid < NT) {
            float s = 0.f;
#pragma unroll
            for (int g = 0; g < 16; ++g) s += tred[g][tid];
            ts[tid] = s;
        }
        if (tid == 0 && mhalf == 0)
            atomicAdd(&acc[512 + K * 8 + b], nred[0] + nred[1] + nred[2] + nred[3]);
    }

    // ---- epilogue: LDS transpose (2 groups of 64 rows) -> coalesced out ----
    float dp[K >= 0 ? K + 1 : 1];
#pragma unroll
    for (int j = 0; j < (K >= 0 ? K + 1 : 1); ++j) dp[j] = 0.f;
#pragma unroll
    for (int g = 0; g < 2; ++g) {
        __syncthreads();   // wt (aliases Ph/Pl) safe / prev group done; ts ready
        if ((wvi >> 1) == g) {
            int rl = (wvi & 1) * 32;
#pragma unroll
            for (int rt = 0; rt < 2; ++rt)
#pragma unroll
                for (int ct = 0; ct < 4; ++ct) {
                    int r0 = rl + rt * 16 + (lane >> 4) * 4;
                    int ccol = ct * 16 + (lane & 15);
#pragma unroll
                    for (int reg = 0; reg < 4; ++reg)
                        wt[(r0 + reg) * WTS + ccol] = ac[rt][ct][reg];
                }
        }
        __syncthreads();
#pragma unroll
        for (int rr = 0; rr < 4; ++rr) {
            int rlocal = rr * 16 + (tid >> 4);
            int rabs = mhalf * 128 + g * 64 + rlocal;
            int col = (tid & 15) * 4;
            const float* src = wt + rlocal * WTS + col;
            float4 wv4 = {src[0], src[1], src[2], src[3]};
            size_t idx = boff + (size_t)rabs * HWn + sbase + col;
            if (K < 0) {
                ushort4 zh4, zl4;
                unsigned short h0 = f2b(wv4.x), h1 = f2b(wv4.y);
                unsigned short h2 = f2b(wv4.z), h3 = f2b(wv4.w);
                zh4.x = h0; zh4.y = h1; zh4.z = h2; zh4.w = h3;
                zl4.x = f2b(wv4.x - b2f(h0)); zl4.y = f2b(wv4.y - b2f(h1));
                zl4.z = f2b(wv4.z - b2f(h2)); zl4.w = f2b(wv4.w - b2f(h3));
                *(ushort4*)(Zh + idx) = zh4;
                *(ushort4*)(Zl + idx) = zl4;
            } else {
                ushort4 zh4 = *(const ushort4*)(Zh + idx);
                ushort4 zl4 = *(const ushort4*)(Zl + idx);
                float z0 = b2f(zh4.x) + b2f(zl4.x), z1 = b2f(zh4.y) + b2f(zl4.y);
                float z2 = b2f(zh4.z) + b2f(zl4.z), z3 = b2f(zh4.w) + b2f(zl4.w);
                float4 wf;
                wf.x = wv4.x - z0 * ts[col + 0];
                wf.y = wv4.y - z1 * ts[col + 1];
                wf.z = wv4.z - z2 * ts[col + 2];
                wf.w = wv4.w - z3 * ts[col + 3];
                *(float4*)(w + idx) = wf;
                float4 vv4 = *(const float4*)(v + idx);
                dp[0] = fmaf(wf.x, vv4.x, dp[0]);
                dp[0] = fmaf(wf.y, vv4.y, dp[0]);
                dp[0] = fmaf(wf.z, vv4.z, dp[0]);
                dp[0] = fmaf(wf.w, vv4.w, dp[0]);
#pragma unroll
                for (int j = 1; j <= (K >= 0 ? K : 0); ++j) {
                    ushort4 u = *(const ushort4*)(Qb + (size_t)(j - 1) * NTOT + idx);
                    dp[j] = fmaf(wf.x, b2f(u.x), dp[j]);
                    dp[j] = fmaf(wf.y, b2f(u.y), dp[j]);
                    dp[j] = fmaf(wf.z, b2f(u.z), dp[j]);
                    dp[j] = fmaf(wf.w, b2f(u.w), dp[j]);
                }
            }
        }
    }
    if (K >= 0) {
#pragma unroll
        for (int j = 0; j <= K; ++j) {
            float q = dp[j];
            for (int off2 = 32; off2 > 0; off2 >>= 1) q += __shfl_down(q, off2);
            if (lane == 0) dred[wvi][j] = q;
        }
        __syncthreads();
        if (tid <= K)
            atomicAdd(&acc[(K * 8 + tid) * 8 + b],
                      dred[0][tid] + dred[1][tid] + dred[2][tid] + dred[3][tid]);
    }
}

// ---------------- expm of 9x9 per batch (fp64); emits combine coeffs ----------
__global__ __launch_bounds__(128) void expm_kernel(const float* __restrict__ acc,
                                                   float* __restrict__ coordsOut) {
    __shared__ double Am[81], Pm[81], Tm[81];
    __shared__ double ssc;
    __shared__ int sn;
    const int b = blockIdx.x;
    const int t = threadIdx.x;
    const int r = t / 9, c = t % 9;
    double m[8];
    m[0] = sqrt((double)acc[512 + b]);
    for (int j = 1; j < 8; ++j) m[j] = sqrt((double)acc[512 + j * 8 + b]) + 1e-12 * m[j - 1];
    if (t < 81) {
        double val = 0.0;
        if (r < 8 && c < 8) {
            if (r <= c) val = TEND * (double)acc[(c * 8 + r) * 8 + b] / (m[r] * m[c]);
            else if (r == c + 1) val = TEND * sqrt((double)acc[512 + r * 8 + b]) / m[c];
        }
        if (r == 0 && c == 8) val = TEND;
        Am[t] = val;
    }
    __syncthreads();
    if (t == 0) {
        double mx = 0.0;
        for (int rr = 0; rr < 9; ++rr) {
            double s = 0.0;
            for (int cc = 0; cc < 9; ++cc) s += fabs(Am[rr * 9 + cc]);
            if (s > mx) mx = s;
        }
        int n = 0;
        while (mx > 0.25 && n < 48) { mx *= 0.5; ++n; }
        double sc = 1.0;
        for (int ii = 0; ii < n; ++ii) sc *= 0.5;
        sn = n; ssc = sc;
    }
    __syncthreads();
    if (t < 81) Am[t] *= ssc;
    __syncthreads();
    if (t < 81) Pm[t] = (r == c) ? 1.0 : 0.0;
    __syncthreads();
    for (int i = 20; i >= 1; --i) {
        if (t < 81) {
            double s = 0.0;
            for (int k = 0; k < 9; ++k) s += Am[r * 9 + k] * Pm[k * 9 + c];
            Tm[t] = ((r == c) ? 1.0 : 0.0) + s / (double)i;
        }
        __syncthreads();
        if (t < 81) Pm[t] = Tm[t];
        __syncthreads();
    }
    int n = sn;
    for (int q = 0; q < n; ++q) {
        if (t < 81) {
            double s = 0.0;
            for (int k = 0; k < 9; ++k) s += Pm[r * 9 + k] * Pm[k * 9 + c];
            Tm[t] = s;
        }
        __syncthreads();
        if (t < 81) Pm[t] = Tm[t];
        __syncthreads();
    }
    if (t < 8) coordsOut[b * 8 + t] = (float)(Pm[t * 9 + 8] * m[0] / m[t]);
}

__device__ inline void unp8(uint4 u, float* f) {
    f[0] = b2f(u.x & 0xFFFFu); f[1] = b2f(u.x >> 16);
    f[2] = b2f(u.y & 0xFFFFu); f[3] = b2f(u.y >> 16);
    f[4] = b2f(u.z & 0xFFFFu); f[5] = b2f(u.z >> 16);
    f[6] = b2f(u.w & 0xFFFFu); f[7] = b2f(u.w >> 16);
}

// ------ out = coeff_0*v + sum_{j=1..7} coeff_j * U_j (bf16) ------
__global__ __launch_bounds__(256) void combine_kernel(const unsigned short* __restrict__ Qb,
                                                      const float* __restrict__ v,
                                                      const float* __restrict__ coords,
                                                      float* __restrict__ out) {
    int b = blockIdx.y;
    const size_t boff = (size_t)b * FB;
    float cf[8];
#pragma unroll
    for (int j = 0; j < 8; ++j) cf[j] = coords[b * 8 + j];
    const float4* vv = (const float4*)(v + boff);
    const uint4* uv[8];
#pragma unroll
    for (int j = 1; j < 8; ++j)
        uv[j] = (const uint4*)(Qb + (size_t)(j - 1) * NTOT + boff);
    int i = blockIdx.x * 256 + threadIdx.x;
    float4* ov = (float4*)(out + boff);
#pragma unroll
    for (int r = 0; r < 2; ++r) {
        int idx = i + r * 65536;
        float4 v0 = vv[2 * idx], v1 = vv[2 * idx + 1];
        float a[8] = {cf[0] * v0.x, cf[0] * v0.y, cf[0] * v0.z, cf[0] * v0.w,
                      cf[0] * v1.x, cf[0] * v1.y, cf[0] * v1.z, cf[0] * v1.w};
#pragma unroll
        for (int j = 1; j < 8; ++j) {
            uint4 u = uv[j][idx];
            float ue[8]; unp8(u, ue);
#pragma unroll
            for (int e = 0; e < 8; ++e) a[e] = fmaf(cf[j], ue[e], a[e]);
        }
        float4 o0 = {a[0], a[1], a[2], a[3]};
        float4 o1 = {a[4], a[5], a[6], a[7]};
        ov[2 * idx] = o0; ov[2 * idx + 1] = o1;
    }
}

extern "C" void kernel_launch(void* const* d_in, const int* in_sizes, int n_in,
                              void* d_out, int out_size, void* d_ws, size_t ws_size,
                              hipStream_t stream) {
    const float* s0 = (const float*)d_in[0];
    const float* v  = (const float*)d_in[1];
    const float* W  = (const float*)d_in[2];
    float* out = (float*)d_out;

    // ws (floats): [acc 576 | coords 64 | pad->1024 | Whs 32768 | Wls 32768 |
    //               Zh bf16 NTOT | Zl bf16 NTOT | Qb bf16 7*NTOT]
    float* ws     = (float*)d_ws;
    float* acc    = ws;
    float* coords = ws + 576;
    unsigned short* Whs = (unsigned short*)(ws + 1024);
    unsigned short* Wls = Whs + 65536;
    unsigned short* Zh  = (unsigned short*)(ws + 1024 + 65536);
    unsigned short* Zl  = Zh + NTOT;
    unsigned short* Qb  = Zh + 2 * (size_t)NTOT;   // 7 bf16 fields
    float* w      = out;   // working A-output (fp32), updated in place per step

    init_kernel<<<dim3(1), dim3(256), 0, stream>>>(ws);
    wsplit_kernel<<<dim3(8, 16), dim3(64), 0, stream>>>(W, Whs, Wls);

    dim3 ga(128, 8), blk(256);
    // Z = W @ s0 (once, bf16 hi/lo)
    step_kernel<-1><<<ga, blk, 0, stream>>>(v, s0, Whs, Wls, Qb, acc, w, Zh, Zl);
#define STEPK(K) step_kernel<K><<<ga, blk, 0, stream>>>(v, s0, Whs, Wls, Qb, acc, w, Zh, Zl);
    STEPK(0) STEPK(1) STEPK(2) STEPK(3) STEPK(4) STEPK(5) STEPK(6) STEPK(7)
#undef STEPK

    expm_kernel<<<dim3(8), dim3(128), 0, stream>>>(acc, coords);
    combine_kernel<<<dim3(256, 8), blk, 0, stream>>>(Qb, v, coords, out);
}